// Round 8
// baseline (10542.744 us; speedup 1.0000x reference)
//
#include <hip/hip_runtime.h>
#include <hip/hip_bf16.h>
#include <cstddef>

typedef __attribute__((ext_vector_type(8))) short bf16x8;
typedef __attribute__((ext_vector_type(4))) float f32x4;
typedef __attribute__((ext_vector_type(4))) unsigned int u32x4;

constexpr int kB = 64;      // batch
constexpr int kS = 1024;    // seq len
constexpr int kH = 512;     // hidden (== input size)
constexpr int kWGL = 32;    // workgroups per layer
constexpr int kUPW = 16;    // hidden units per WG (48 gate rows = 3 N-tiles)
constexpr int kWst = 520;   // LDS weight row stride (elems; 16B-aligned, uniform banks)
constexpr int kSpinCap = 1 << 16;         // fail-fast
constexpr unsigned kDone4 = 0x01010101u;  // 4 done-bytes

__device__ __forceinline__ unsigned short f2bf(float f) {
  unsigned int u = __float_as_uint(f);
  u += 0x7FFFu + ((u >> 16) & 1u);   // round-to-nearest-even
  return (unsigned short)(u >> 16);
}

// ---------------- coherent (IF$-level) access helpers ----------------
__device__ __forceinline__ void st_u32_coh(unsigned int* p, unsigned int v) {
  asm volatile("global_store_dword %0, %1, off sc0 sc1" ::"v"(p), "v"(v) : "memory");
}
__device__ __forceinline__ void st_u64_coh(void* p, unsigned long long v) {
  asm volatile("global_store_dwordx2 %0, %1, off sc0 sc1" ::"v"(p), "v"(v) : "memory");
}
__device__ __forceinline__ void st_u8_coh(unsigned char* p, unsigned int v) {
  asm volatile("global_store_byte %0, %1, off sc0 sc1" ::"v"(p), "v"(v) : "memory");
}

#define COH_LD16(dst, p, OFF)                                             \
  asm volatile("global_load_dwordx4 %0, %1, off offset:" #OFF " sc0 sc1"  \
               : "=v"(dst) : "v"(p) : "memory")

// issue 16 coherent 16B loads (one 512-elem bf16 row as MFMA A-fragments)
__device__ __forceinline__ void coh_issue16(const unsigned short* p, bf16x8* d) {
  COH_LD16(d[0],  p, 0);   COH_LD16(d[1],  p, 64);  COH_LD16(d[2],  p, 128);
  COH_LD16(d[3],  p, 192); COH_LD16(d[4],  p, 256); COH_LD16(d[5],  p, 320);
  COH_LD16(d[6],  p, 384); COH_LD16(d[7],  p, 448); COH_LD16(d[8],  p, 512);
  COH_LD16(d[9],  p, 576); COH_LD16(d[10], p, 640); COH_LD16(d[11], p, 704);
  COH_LD16(d[12], p, 768); COH_LD16(d[13], p, 832); COH_LD16(d[14], p, 896);
  COH_LD16(d[15], p, 960);
}

__device__ __forceinline__ void wait_vm0(void) {
  asm volatile("s_waitcnt vmcnt(0)" ::: "memory");
  __builtin_amdgcn_sched_barrier(0);  // rule #18
}

// single-thread poll of 32 contiguous done-bytes (2 x dwordx4), capped
__device__ __forceinline__ int poll32(const unsigned char* p) {
  for (int i = 0; i < kSpinCap; ++i) {
    u32x4 a, b;
    asm volatile(
        "global_load_dwordx4 %0, %2, off sc0 sc1\n\t"
        "global_load_dwordx4 %1, %2, off offset:16 sc0 sc1\n\t"
        "s_waitcnt vmcnt(0)"
        : "=v"(a), "=v"(b) : "v"(p) : "memory");
    if (a[0] == kDone4 && a[1] == kDone4 && a[2] == kDone4 && a[3] == kDone4 &&
        b[0] == kDone4 && b[1] == kDone4 && b[2] == kDone4 && b[3] == kDone4)
      return 1;
  }
  return 0;
}

// ---------------- init: coherent zeros (flag arrays) ----------------
__global__ void init_coh(unsigned int* __restrict__ zbase, int n) {
  int i = blockIdx.x * blockDim.x + threadIdx.x;
  if (i < n) st_u32_coh(zbase + i, 0u);
}

// ---------------- fp32 -> bf16 converts ----------------
__global__ void cvt_f32_bf16(const float* __restrict__ in,
                             unsigned short* __restrict__ out, int n4) {
  int i = blockIdx.x * blockDim.x + threadIdx.x;
  if (i >= n4) return;
  float4 v = ((const float4*)in)[i];
  ushort4 o;
  o.x = f2bf(v.x); o.y = f2bf(v.y); o.z = f2bf(v.z); o.w = f2bf(v.w);
  ((ushort4*)out)[i] = o;
}

// x [B][S][I] fp32 -> xbf [S][B][I] bf16 (time-major)
__global__ void cvt_x_t(const float* __restrict__ in,
                        unsigned short* __restrict__ out, int n4) {
  int i4 = blockIdx.x * blockDim.x + threadIdx.x;
  if (i4 >= n4) return;
  int d = i4 * 4;
  int i = d & (kH - 1);
  int rem = d / kH;
  int b = rem & (kB - 1);
  int s = rem / kB;
  float4 v = *(const float4*)(in + ((size_t)b * kS + s) * kH + i);
  ushort4 o;
  o.x = f2bf(v.x); o.y = f2bf(v.y); o.z = f2bf(v.z); o.w = f2bf(v.w);
  *(ushort4*)(out + (size_t)d) = o;
}

// ---------------- fused persistent 2-layer GRU ----------------
// 64 blocks: 0..31 layer 0, 32..63 layer 1. Each WG owns 16 hidden units
// (48 gate rows = 3 MFMA N-tiles). W_hh in VGPR B-fragments; W_ih in LDS.
// h broadcast via IF$ (sc0sc1); per-WG done-bytes polled by one thread.
__launch_bounds__(256, 1)
__global__ void gru_fused(const unsigned short* __restrict__ xbf,   // [S][B][H]
                          const unsigned short* __restrict__ wih0,  // [3H][H]
                          const unsigned short* __restrict__ whh0,
                          const unsigned short* __restrict__ wih1,
                          const unsigned short* __restrict__ whh1,
                          const float* __restrict__ bih0, const float* __restrict__ bhh0,
                          const float* __restrict__ bih1, const float* __restrict__ bhh1,
                          unsigned short* __restrict__ hs0,    // [S][B][H] bf16
                          unsigned short* __restrict__ h1buf,  // [2][B][H] bf16
                          unsigned char* __restrict__ f0,      // [S][32] done-bytes L0
                          unsigned char* __restrict__ f1,      // [S][32] done-bytes L1
                          float* __restrict__ out) {
  const int tid  = threadIdx.x;
  const int lane = tid & 63;
  const int wv   = tid >> 6;                 // wave 0..3
  const int layer = blockIdx.x >> 5;
  const int wg    = blockIdx.x & (kWGL - 1);
  const int j0    = wg * kUPW;

  const unsigned short* wih = layer ? wih1 : wih0;
  const unsigned short* whh = layer ? whh1 : whh0;
  const float* bih = layer ? bih1 : bih0;
  const float* bhh = layer ? bhh1 : bhh0;

  __shared__ unsigned short wlds[48][kWst];  // W_ih rows (3 gates x 16 units)
  __shared__ float gxl[64][49];              // padded exchange buffers
  __shared__ float ghl[64][49];

  // ---- stage W_ih -> LDS ----
  for (int idx = tid; idx < 48 * 64; idx += 256) {
    int row = idx >> 6, c16 = idx & 63;
    int g = row >> 4, u = row & 15;
    *(bf16x8*)&wlds[row][c16 * 8] =
        *(const bf16x8*)(wih + ((size_t)g * kH + j0 + u) * kH + c16 * 8);
  }

  // ---- W_hh B-fragments in VGPRs (3 tiles x 16 K-steps = 192 VGPR) ----
  const int n_  = lane & 15, hi_ = lane >> 4;
  bf16x8 bhf[3][16];
#pragma unroll
  for (int g = 0; g < 3; ++g)
#pragma unroll
    for (int kk = 0; kk < 16; ++kk)
      bhf[g][kk] = *(const bf16x8*)(whh + ((size_t)g * kH + j0 + n_) * kH + kk * 32 + hi_ * 8);
  __syncthreads();  // wlds ready

  // gates: wave wv handles units j0+wv*4..+3 for batch gb=lane
  const int gb = lane;
  const int u4 = wv * 4;
  const f32x4 bxr = *(const f32x4*)(bih + 0 * kH + j0 + u4);
  const f32x4 bxz = *(const f32x4*)(bih + 1 * kH + j0 + u4);
  const f32x4 bxn = *(const f32x4*)(bih + 2 * kH + j0 + u4);
  const f32x4 bhr = *(const f32x4*)(bhh + 0 * kH + j0 + u4);
  const f32x4 bhz = *(const f32x4*)(bhh + 1 * kH + j0 + u4);
  const f32x4 bhn = *(const f32x4*)(bhh + 2 * kH + j0 + u4);
  f32x4 hprev = {0.f, 0.f, 0.f, 0.f};

  // A-fragment coords: wave wv owns batches wv*16..+15
  const int abat = wv * 16 + n_;
  const int ahi  = hi_ * 8;
  const int mb   = wv * 16 + hi_ * 4;

  unsigned char* myf = layer ? f1 : f0;
  int dead = 0;

  for (int t = 0; t < kS; ++t) {
    // ---- layer 0: input GEMM pre-flag (x L2-cached, B-frags from LDS) ----
    f32x4 agx0 = {0,0,0,0}, agx1 = {0,0,0,0}, agx2 = {0,0,0,0};
    if (layer == 0) {
      const unsigned short* pAX = xbf + ((size_t)t * kB + abat) * kH + ahi;
#pragma unroll
      for (int kk = 0; kk < 16; ++kk) {
        bf16x8 ax = *(const bf16x8*)(pAX + kk * 32);
        agx0 = __builtin_amdgcn_mfma_f32_16x16x32_bf16(ax, *(const bf16x8*)&wlds[ 0 + n_][kk * 32 + ahi], agx0, 0, 0, 0);
        agx1 = __builtin_amdgcn_mfma_f32_16x16x32_bf16(ax, *(const bf16x8*)&wlds[16 + n_][kk * 32 + ahi], agx1, 0, 0, 0);
        agx2 = __builtin_amdgcn_mfma_f32_16x16x32_bf16(ax, *(const bf16x8*)&wlds[32 + n_][kk * 32 + ahi], agx2, 0, 0, 0);
      }
#pragma unroll
      for (int r = 0; r < 4; ++r) {
        gxl[mb + r][ 0 + n_] = agx0[r];
        gxl[mb + r][16 + n_] = agx1[r];
        gxl[mb + r][32 + n_] = agx2[r];
      }
    }

    // ---- wait: one poller per dependency ----
    int ok = 1;
    if (layer == 0) {
      if (t > 0 && tid == 0) ok = poll32(f0 + (size_t)(t - 1) * kWGL);
    } else {
      if (tid == 0) ok = poll32(f0 + (size_t)t * kWGL);
      else if (t > 0 && tid == 64) ok = poll32(f1 + (size_t)(t - 1) * kWGL);
    }
    if (!__syncthreads_and(ok)) { dead = 1; break; }

    // ---- post-flag: coherent A loads ----
    bf16x8 ahv[16], axv[16];
    if (t > 0) {
      const unsigned short* pAH =
          (layer == 0) ? hs0 + ((size_t)(t - 1) * kB + abat) * kH + ahi
                       : h1buf + ((size_t)((t - 1) & 1) * kB + abat) * kH + ahi;
      coh_issue16(pAH, ahv);
    }
    if (layer == 1)
      coh_issue16(hs0 + ((size_t)t * kB + abat) * kH + ahi, axv);
    wait_vm0();

    // ---- GEMMs ----
    if (layer == 1) {
#pragma unroll
      for (int kk = 0; kk < 16; ++kk) {
        agx0 = __builtin_amdgcn_mfma_f32_16x16x32_bf16(axv[kk], *(const bf16x8*)&wlds[ 0 + n_][kk * 32 + ahi], agx0, 0, 0, 0);
        agx1 = __builtin_amdgcn_mfma_f32_16x16x32_bf16(axv[kk], *(const bf16x8*)&wlds[16 + n_][kk * 32 + ahi], agx1, 0, 0, 0);
        agx2 = __builtin_amdgcn_mfma_f32_16x16x32_bf16(axv[kk], *(const bf16x8*)&wlds[32 + n_][kk * 32 + ahi], agx2, 0, 0, 0);
      }
    }
    f32x4 agh0 = {0,0,0,0}, agh1 = {0,0,0,0}, agh2 = {0,0,0,0};
    if (t > 0) {
#pragma unroll
      for (int kk = 0; kk < 16; ++kk) {
        agh0 = __builtin_amdgcn_mfma_f32_16x16x32_bf16(ahv[kk], bhf[0][kk], agh0, 0, 0, 0);
        agh1 = __builtin_amdgcn_mfma_f32_16x16x32_bf16(ahv[kk], bhf[1][kk], agh1, 0, 0, 0);
        agh2 = __builtin_amdgcn_mfma_f32_16x16x32_bf16(ahv[kk], bhf[2][kk], agh2, 0, 0, 0);
      }
    }
#pragma unroll
    for (int r = 0; r < 4; ++r) {
      ghl[mb + r][ 0 + n_] = agh0[r];
      ghl[mb + r][16 + n_] = agh1[r];
      ghl[mb + r][32 + n_] = agh2[r];
      if (layer == 1) {
        gxl[mb + r][ 0 + n_] = agx0[r];
        gxl[mb + r][16 + n_] = agx1[r];
        gxl[mb + r][32 + n_] = agx2[r];
      }
    }
    __syncthreads();

    // ---- gates (all 4 waves, 4 units each per batch lane) ----
    f32x4 hnew;
#pragma unroll
    for (int j = 0; j < 4; ++j) {
      const float xr = gxl[gb][ 0 + u4 + j] + bxr[j];
      const float xz = gxl[gb][16 + u4 + j] + bxz[j];
      const float xn = gxl[gb][32 + u4 + j] + bxn[j];
      const float hr = ghl[gb][ 0 + u4 + j] + bhr[j];
      const float hz = ghl[gb][16 + u4 + j] + bhz[j];
      const float hn = ghl[gb][32 + u4 + j] + bhn[j];
      const float r = 1.0f / (1.0f + __expf(-(xr + hr)));
      const float z = 1.0f / (1.0f + __expf(-(xz + hz)));
      const float nv = tanhf(xn + r * hn);
      hnew[j] = (1.0f - z) * nv + z * hprev[j];
    }
    hprev = hnew;

    // ---- publish (each thread: its 4 units for batch gb) ----
    unsigned long long pk =
        (unsigned long long)f2bf(hnew[0]) |
        ((unsigned long long)f2bf(hnew[1]) << 16) |
        ((unsigned long long)f2bf(hnew[2]) << 32) |
        ((unsigned long long)f2bf(hnew[3]) << 48);
    if (layer == 0) {
      st_u64_coh(hs0 + ((size_t)t * kB + gb) * kH + j0 + u4, pk);
    } else {
      st_u64_coh(h1buf + ((size_t)(t & 1) * kB + gb) * kH + j0 + u4, pk);
      *(f32x4*)(out + ((size_t)gb * kS + t) * kH + j0 + u4) = hnew;  // [b][t][h]
    }
    asm volatile("s_waitcnt vmcnt(0)" ::: "memory");  // per-wave drain (IF$ ack)
    __syncthreads();                                  // all waves drained
    if (tid == 0)
      st_u8_coh(myf + (size_t)t * kWGL + wg, 1u);
  }

  // ---- h_n epilogue ----
  if (!dead)
    *(f32x4*)(out + (size_t)kB * kS * kH + (size_t)layer * kB * kH +
              (size_t)gb * kH + j0 + u4) = hprev;
}

extern "C" void kernel_launch(void* const* d_in, const int* in_sizes, int n_in,
                              void* d_out, int out_size, void* d_ws, size_t ws_size,
                              hipStream_t stream) {
  const float* x     = (const float*)d_in[0];
  const float* w_ih0 = (const float*)d_in[1];
  const float* w_hh0 = (const float*)d_in[2];
  const float* b_ih0 = (const float*)d_in[3];
  const float* b_hh0 = (const float*)d_in[4];
  const float* w_ih1 = (const float*)d_in[5];
  const float* w_hh1 = (const float*)d_in[6];
  const float* b_ih1 = (const float*)d_in[7];
  const float* b_hh1 = (const float*)d_in[8];
  float* out = (float*)d_out;

  // ---- workspace layout (ushort elems unless noted) ----
  unsigned short* ws = (unsigned short*)d_ws;
  const size_t nX = (size_t)kB * kS * kH;   // 33,554,432
  const size_t nW = (size_t)3 * kH * kH;    // 786,432
  unsigned short* xbf   = ws;
  unsigned short* wih0b = xbf + nX;
  unsigned short* whh0b = wih0b + nW;
  unsigned short* wih1b = whh0b + nW;
  unsigned short* whh1b = wih1b + nW;
  unsigned short* hs0   = whh1b + nW;               // nX
  unsigned short* h1buf = hs0 + nX;                 // 2*B*H
  unsigned char*  f0    = (unsigned char*)(h1buf + 2 * kB * kH);  // S*32 bytes
  unsigned char*  f1    = f0 + (size_t)kS * kWGL;                 // S*32 bytes

  // zero both flag arrays (contiguous, 64KB) coherently each launch
  {
    int nz = (2 * kS * kWGL) / 4;   // 16384 u32
    init_coh<<<(nz + 255) / 256, 256, 0, stream>>>((unsigned int*)f0, nz);
  }
  // converts
  {
    int n4 = (int)(nX / 4);
    cvt_x_t<<<n4 / 256, 256, 0, stream>>>(x, xbf, n4);
    int w4 = (int)(nW / 4);
    cvt_f32_bf16<<<w4 / 256, 256, 0, stream>>>(w_ih0, wih0b, w4);
    cvt_f32_bf16<<<w4 / 256, 256, 0, stream>>>(w_hh0, whh0b, w4);
    cvt_f32_bf16<<<w4 / 256, 256, 0, stream>>>(w_ih1, wih1b, w4);
    cvt_f32_bf16<<<w4 / 256, 256, 0, stream>>>(w_hh1, whh1b, w4);
  }

  // fused persistent GRU — 64 blocks (co-residency trivial)
  gru_fused<<<dim3(2 * kWGL), dim3(256), 0, stream>>>(
      xbf, wih0b, whh0b, wih1b, whh1b,
      b_ih0, b_hh0, b_ih1, b_hh1,
      hs0, h1buf, f0, f1, out);
}

// Round 9
// 9983.086 us; speedup vs baseline: 1.0561x; 1.0561x over previous
//
#include <hip/hip_runtime.h>
#include <hip/hip_bf16.h>
#include <cstddef>

typedef __attribute__((ext_vector_type(8))) short bf16x8;
typedef __attribute__((ext_vector_type(4))) float f32x4;
typedef __attribute__((ext_vector_type(4))) unsigned int u32x4;

constexpr int kB = 64;      // batch
constexpr int kS = 1024;    // seq len
constexpr int kH = 512;     // hidden (== input size)
constexpr int kNWGL = 128;  // workgroups per layer
constexpr int kUPW = 4;     // hidden units per workgroup (12 gate rows)
constexpr int kNC = 8;      // sub-counters per step
constexpr unsigned kWant = kNWGL / kNC;  // 16 producers per sub-counter
constexpr int kSpinCap = 1 << 16;        // fail-fast

__device__ __forceinline__ unsigned short f2bf(float f) {
  unsigned int u = __float_as_uint(f);
  u += 0x7FFFu + ((u >> 16) & 1u);   // round-to-nearest-even
  return (unsigned short)(u >> 16);
}

// ---------------- coherence helpers ----------------
// Publish: device-scope atomic swap executes AT the IF$ (memory-side cache).
// Ack (vmcnt) = IF$ execution, not DRAM write-through; line stays IF$-resident.
__device__ __forceinline__ void st_u64_ifc(void* p, unsigned long long v) {
  asm volatile("global_atomic_swap_x2 %0, %1, off sc1" ::"v"(p), "v"(v)
               : "memory");
}
__device__ __forceinline__ void st_u32_coh(unsigned int* p, unsigned int v) {
  asm volatile("global_store_dword %0, %1, off sc0 sc1" ::"v"(p), "v"(v)
               : "memory");
}

// coherent (L1+L2-bypass) 16B load at literal byte offset — for bufs with
// address reuse within a launch (h1buf), where L2 could hold stale lines
#define COH_LD16(dst, p, OFF)                                             \
  asm volatile("global_load_dwordx4 %0, %1, off offset:" #OFF " sc0 sc1"  \
               : "=v"(dst) : "v"(p) : "memory")

__device__ __forceinline__ void coh_issue16(const unsigned short* p, bf16x8* d) {
  COH_LD16(d[0],  p, 0);   COH_LD16(d[1],  p, 64);  COH_LD16(d[2],  p, 128);
  COH_LD16(d[3],  p, 192); COH_LD16(d[4],  p, 256); COH_LD16(d[5],  p, 320);
  COH_LD16(d[6],  p, 384); COH_LD16(d[7],  p, 448); COH_LD16(d[8],  p, 512);
  COH_LD16(d[9],  p, 576); COH_LD16(d[10], p, 640); COH_LD16(d[11], p, 704);
  COH_LD16(d[12], p, 768); COH_LD16(d[13], p, 832); COH_LD16(d[14], p, 896);
  COH_LD16(d[15], p, 960);
}

// plain cached 16-fragment load — for hs0 (unique address per step within a
// launch: L2 cold-miss fills from IF$, which holds the atomic-published data;
// 16 WGs/XCD then share the L2 copy)
__device__ __forceinline__ void plain_issue16(const unsigned short* p, bf16x8* d) {
#pragma unroll
  for (int i = 0; i < 16; ++i) d[i] = *(const bf16x8*)(p + i * 32);
}

__device__ __forceinline__ void wait_vm0(void) {
  asm volatile("s_waitcnt vmcnt(0)" ::: "memory");
  __builtin_amdgcn_sched_barrier(0);  // rule #18
}

// single-thread poll of 8 contiguous sub-counters (32B), capped fail-fast
__device__ __forceinline__ int poll8(const unsigned int* p) {
  for (int i = 0; i < kSpinCap; ++i) {
    u32x4 a, b;
    asm volatile(
        "global_load_dwordx4 %0, %2, off sc0 sc1\n\t"
        "global_load_dwordx4 %1, %2, off offset:16 sc0 sc1\n\t"
        "s_waitcnt vmcnt(0)"
        : "=v"(a), "=v"(b) : "v"(p) : "memory");
    if (a[0] == kWant && a[1] == kWant && a[2] == kWant && a[3] == kWant &&
        b[0] == kWant && b[1] == kWant && b[2] == kWant && b[3] == kWant)
      return 1;
  }
  return 0;
}

// ---------------- init: coherent zeros (counters) ----------------
__global__ void init_coh(unsigned int* __restrict__ zbase, int n) {
  int i = blockIdx.x * blockDim.x + threadIdx.x;
  if (i < n) st_u32_coh(zbase + i, 0u);
}

// ---------------- fp32 -> bf16 converts ----------------
__global__ void cvt_f32_bf16(const float* __restrict__ in,
                             unsigned short* __restrict__ out, int n4) {
  int i = blockIdx.x * blockDim.x + threadIdx.x;
  if (i >= n4) return;
  float4 v = ((const float4*)in)[i];
  ushort4 o;
  o.x = f2bf(v.x); o.y = f2bf(v.y); o.z = f2bf(v.z); o.w = f2bf(v.w);
  ((ushort4*)out)[i] = o;
}

// x [B][S][I] fp32 -> xbf [S][B][I] bf16 (time-major)
__global__ void cvt_x_t(const float* __restrict__ in,
                        unsigned short* __restrict__ out, int n4) {
  int i4 = blockIdx.x * blockDim.x + threadIdx.x;
  if (i4 >= n4) return;
  int d = i4 * 4;
  int i = d & (kH - 1);
  int rem = d / kH;
  int b = rem & (kB - 1);
  int s = rem / kB;
  float4 v = *(const float4*)(in + ((size_t)b * kS + s) * kH + i);
  ushort4 o;
  o.x = f2bf(v.x); o.y = f2bf(v.y); o.z = f2bf(v.z); o.w = f2bf(v.w);
  *(ushort4*)(out + (size_t)d) = o;
}

// ---------------- fused persistent 2-layer GRU (R7 skeleton) ----------------
// blocks 0..127 = layer 0, 128..255 = layer 1. Each WG: 4 hidden units
// (12 gate rows) as VGPR B-fragments. Publish = atomic-swap@IF$; flags = 8
// agent-scope sub-counters, one poller thread per dependency.
__launch_bounds__(256, 1)
__global__ void gru_fused(const unsigned short* __restrict__ xbf,   // [S][B][H]
                          const unsigned short* __restrict__ wih0,  // [3H][H]
                          const unsigned short* __restrict__ whh0,
                          const unsigned short* __restrict__ wih1,
                          const unsigned short* __restrict__ whh1,
                          const float* __restrict__ bih0, const float* __restrict__ bhh0,
                          const float* __restrict__ bih1, const float* __restrict__ bhh1,
                          unsigned short* __restrict__ hs0,    // [S][B][H] bf16
                          unsigned short* __restrict__ h1buf,  // [2][B][H] bf16
                          unsigned int* __restrict__ cnt0,     // [S][8]
                          unsigned int* __restrict__ cnt1,     // [S][8]
                          float* __restrict__ out) {
  const int tid  = threadIdx.x;
  const int lane = tid & 63;
  const int wv   = tid >> 6;            // wave 0..3
  const int layer = blockIdx.x >> 7;
  const int wg    = blockIdx.x & (kNWGL - 1);
  const int j0    = wg * kUPW;

  const unsigned short* wih = layer ? wih1 : wih0;
  const unsigned short* whh = layer ? whh1 : whh0;
  const float* bih = layer ? bih1 : bih0;
  const float* bhh = layer ? bhh1 : bhh0;

  // ---- B-fragments (weights) in registers, loaded once ----
  bf16x8 bx[16], bh[16];
  {
    const int n = lane & 15, hi = lane >> 4;
    if (n < 12) {
      const int orig = (n >> 2) * kH + j0 + (n & 3);  // gate*512 + unit
      const unsigned short* pX = wih + (size_t)orig * kH + hi * 8;
      const unsigned short* pH = whh + (size_t)orig * kH + hi * 8;
#pragma unroll
      for (int kk = 0; kk < 16; ++kk) {
        bx[kk] = *(const bf16x8*)(pX + kk * 32);
        bh[kk] = *(const bf16x8*)(pH + kk * 32);
      }
    } else {
      bf16x8 z = {0, 0, 0, 0, 0, 0, 0, 0};
#pragma unroll
      for (int kk = 0; kk < 16; ++kk) { bx[kk] = z; bh[kk] = z; }
    }
  }

  // gate-phase assignment: thread -> (batch gb, unit gu)
  const int gb = tid & 63;
  const int gu = wv;
  const float bihr = bih[j0 + gu], bihz = bih[kH + j0 + gu], bihn = bih[2 * kH + j0 + gu];
  const float bhhr = bhh[j0 + gu], bhhz = bhh[kH + j0 + gu], bhhn = bhh[2 * kH + j0 + gu];
  float hprev = 0.0f;

  __shared__ float gxl[2][64][17];   // double-buffered exchange (parity t&1)
  __shared__ float ghl[2][64][17];
  __shared__ unsigned short hl[64][4];
  __shared__ float hlf[64][4];

  const int b0   = wv * 16;             // M-tile batch base for this wave
  const int arow = b0 + (lane & 15);    // A row = batch
  const int ahi  = (lane >> 4) * 8;     // k sub-offset
  const int n_   = lane & 15;
  const int mb   = b0 + (lane >> 4) * 4;

  unsigned int* mycnt = layer ? cnt1 : cnt0;

  for (int t = 0; t < kS; ++t) {
    const int pb = t & 1;

    // ---- layer 0: input GEMM BEFORE the wait (x L2-cached, flag-free) ----
    f32x4 accx = {0.f, 0.f, 0.f, 0.f};
    if (layer == 0) {
      const unsigned short* pAX = xbf + ((size_t)t * kB + arow) * kH + ahi;
#pragma unroll
      for (int kk = 0; kk < 16; ++kk) {
        bf16x8 ax = *(const bf16x8*)(pAX + kk * 32);
        accx = __builtin_amdgcn_mfma_f32_16x16x32_bf16(ax, bx[kk], accx, 0, 0, 0);
      }
#pragma unroll
      for (int r = 0; r < 4; ++r) gxl[pb][mb + r][n_] = accx[r];
    }

    // ---- wait: single poller per dependency ----
    int ok = 1;
    if (layer == 0) {
      if (t > 0 && tid == 0) ok = poll8(cnt0 + (size_t)(t - 1) * kNC);
    } else {
      if (tid == 0) ok = poll8(cnt0 + (size_t)t * kNC);
      else if (t > 0 && tid == 64) ok = poll8(cnt1 + (size_t)(t - 1) * kNC);
    }
    if (!__syncthreads_and(ok)) break;  // fail-fast (protocol fault)

    // ---- recurrent (+L1 input) GEMMs ----
    f32x4 acch = {0.f, 0.f, 0.f, 0.f};
    if (layer == 0) {
      if (t > 0) {
        bf16x8 ah[16];
        plain_issue16(hs0 + ((size_t)(t - 1) * kB + arow) * kH + ahi, ah);
#pragma unroll
        for (int kk = 0; kk < 16; ++kk)
          acch = __builtin_amdgcn_mfma_f32_16x16x32_bf16(ah[kk], bh[kk], acch, 0, 0, 0);
      }
    } else {
      bf16x8 axv[16];
      plain_issue16(hs0 + ((size_t)t * kB + arow) * kH + ahi, axv);
      if (t > 0) {
        bf16x8 ahv[16];
        coh_issue16(h1buf + ((size_t)((t - 1) & 1) * kB + arow) * kH + ahi, ahv);
        wait_vm0();
#pragma unroll
        for (int kk = 0; kk < 16; ++kk) {
          accx = __builtin_amdgcn_mfma_f32_16x16x32_bf16(axv[kk], bx[kk], accx, 0, 0, 0);
          acch = __builtin_amdgcn_mfma_f32_16x16x32_bf16(ahv[kk], bh[kk], acch, 0, 0, 0);
        }
      } else {
#pragma unroll
        for (int kk = 0; kk < 16; ++kk)
          accx = __builtin_amdgcn_mfma_f32_16x16x32_bf16(axv[kk], bx[kk], accx, 0, 0, 0);
      }
#pragma unroll
      for (int r = 0; r < 4; ++r) gxl[pb][mb + r][n_] = accx[r];
    }
#pragma unroll
    for (int r = 0; r < 4; ++r) ghl[pb][mb + r][n_] = acch[r];
    __syncthreads();

    // ---- gate math (fp32) ----
    {
      const float xr = gxl[pb][gb][gu]     + bihr;
      const float xz = gxl[pb][gb][4 + gu] + bihz;
      const float xn = gxl[pb][gb][8 + gu] + bihn;
      const float hr = ghl[pb][gb][gu]     + bhhr;
      const float hzv = ghl[pb][gb][4 + gu] + bhhz;
      const float hn = ghl[pb][gb][8 + gu] + bhhn;
      const float r = 1.0f / (1.0f + __expf(-(xr + hr)));
      const float z = 1.0f / (1.0f + __expf(-(xz + hzv)));
      const float nn = tanhf(xn + r * hn);
      const float hnew = (1.0f - z) * nn + z * hprev;
      hprev = hnew;
      hl[gb][gu] = f2bf(hnew);
      hlf[gb][gu] = hnew;
      if (t == kS - 1)  // h_n epilogue
        out[(size_t)kB * kS * kH + (size_t)layer * kB * kH + (size_t)gb * kH + j0 + gu] = hnew;
    }
    __syncthreads();

    // ---- publish via atomic-swap@IF$ (wave 0), drain, flag — no barrier ----
    if (tid < 64) {
      unsigned long long pk = *(const unsigned long long*)&hl[tid][0];
      if (layer == 0) {
        st_u64_ifc(hs0 + ((size_t)t * kB + tid) * kH + j0, pk);
      } else {
        st_u64_ifc(h1buf + ((size_t)(t & 1) * kB + tid) * kH + j0, pk);
        float4 o4 = *(const float4*)&hlf[tid][0];
        *(float4*)(out + ((size_t)tid * kS + t) * kH + j0) = o4;  // [b][t][h]
      }
      // wave-level drain: vmcnt is per-wave; all publishes are wave-0 ops
      asm volatile("s_waitcnt vmcnt(0)" ::: "memory");
    }
    if (tid == 0)
      __hip_atomic_fetch_add(mycnt + (size_t)t * kNC + (wg & (kNC - 1)), 1u,
                             __ATOMIC_RELAXED, __HIP_MEMORY_SCOPE_AGENT);
    // waves 1-3 already running ahead into next gx (double-buffered LDS)
  }
}

extern "C" void kernel_launch(void* const* d_in, const int* in_sizes, int n_in,
                              void* d_out, int out_size, void* d_ws, size_t ws_size,
                              hipStream_t stream) {
  const float* x     = (const float*)d_in[0];
  const float* w_ih0 = (const float*)d_in[1];
  const float* w_hh0 = (const float*)d_in[2];
  const float* b_ih0 = (const float*)d_in[3];
  const float* b_hh0 = (const float*)d_in[4];
  const float* w_ih1 = (const float*)d_in[5];
  const float* w_hh1 = (const float*)d_in[6];
  const float* b_ih1 = (const float*)d_in[7];
  const float* b_hh1 = (const float*)d_in[8];
  float* out = (float*)d_out;

  // ---- workspace layout (ushort elements unless noted) ----
  unsigned short* ws = (unsigned short*)d_ws;
  const size_t nX = (size_t)kB * kS * kH;   // 33,554,432
  const size_t nW = (size_t)3 * kH * kH;    // 786,432
  unsigned short* xbf   = ws;
  unsigned short* wih0b = xbf + nX;
  unsigned short* whh0b = wih0b + nW;
  unsigned short* wih1b = whh0b + nW;
  unsigned short* whh1b = wih1b + nW;
  unsigned short* hs0   = whh1b + nW;             // nX elems
  unsigned short* h1buf = hs0 + nX;               // 2*B*H
  unsigned int*   cnt0  = (unsigned int*)(h1buf + 2 * kB * kH);  // S*8
  unsigned int*   cnt1  = cnt0 + (size_t)kS * kNC;               // S*8

  // coherent zero-init of counters each launch (replay determinism)
  {
    int nz = 2 * kS * kNC;   // 16384 u32
    init_coh<<<(nz + 255) / 256, 256, 0, stream>>>(cnt0, nz);
  }

  // converts
  {
    int n4 = (int)(nX / 4);
    cvt_x_t<<<n4 / 256, 256, 0, stream>>>(x, xbf, n4);
    int w4 = (int)(nW / 4);
    cvt_f32_bf16<<<w4 / 256, 256, 0, stream>>>(w_ih0, wih0b, w4);
    cvt_f32_bf16<<<w4 / 256, 256, 0, stream>>>(w_hh0, whh0b, w4);
    cvt_f32_bf16<<<w4 / 256, 256, 0, stream>>>(w_ih1, wih1b, w4);
    cvt_f32_bf16<<<w4 / 256, 256, 0, stream>>>(w_hh1, whh1b, w4);
  }

  // fused persistent GRU — plain launch (256 blocks on 256 CUs, 1/CU)
  gru_fused<<<dim3(2 * kNWGL), dim3(256), 0, stream>>>(
      xbf, wih0b, whh0b, wih1b, whh1b,
      b_ih0, b_hh0, b_ih1, b_hh1,
      hs0, h1buf, cnt0, cnt1, out);
}

// Round 10
// 8394.504 us; speedup vs baseline: 1.2559x; 1.1892x over previous
//
#include <hip/hip_runtime.h>
#include <hip/hip_bf16.h>
#include <cstddef>

typedef __attribute__((ext_vector_type(8))) short bf16x8;
typedef __attribute__((ext_vector_type(4))) float f32x4;
typedef __attribute__((ext_vector_type(4))) unsigned int u32x4;

constexpr int kB = 64;      // batch
constexpr int kS = 1024;    // seq len
constexpr int kH = 512;     // hidden (== input size)
constexpr int kNWGL = 128;  // workgroups per layer
constexpr int kUPW = 4;     // hidden units per workgroup (12 gate rows)
constexpr unsigned kSentB = 0xFFC0FFC0u;  // 2x bf16 NaN — impossible for real h
constexpr unsigned kSentF = 0xFFC00000u;  // f32 NaN — impossible for real h
constexpr int kPollCap = 1 << 14;         // fail-fast bail (no watchdog hang)

__device__ __forceinline__ unsigned short f2bf(float f) {
  unsigned int u = __float_as_uint(f);
  u += 0x7FFFu + ((u >> 16) & 1u);   // round-to-nearest-even
  return (unsigned short)(u >> 16);
}

// ---------------- coherent (IF$-level) helpers: sc0 sc1 = bypass L1+L2 ----------------
__device__ __forceinline__ void st_u64_coh(void* p, unsigned long long v) {
  asm volatile("global_store_dwordx2 %0, %1, off sc0 sc1" ::"v"(p), "v"(v) : "memory");
}
__device__ __forceinline__ void st_f32x4_coh(void* p, f32x4 v) {
  asm volatile("global_store_dwordx4 %0, %1, off sc0 sc1" ::"v"(p), "v"(v) : "memory");
}

#define COH_LD16(dst, p, OFF)                                             \
  asm volatile("global_load_dwordx4 %0, %1, off offset:" #OFF " sc0 sc1"  \
               : "=v"(dst) : "v"(p) : "memory")

__device__ __forceinline__ void wait_vm0(void) {
  asm volatile("s_waitcnt vmcnt(0)" ::: "memory");
  __builtin_amdgcn_sched_barrier(0);  // rule #18
}

// poll one 512-elem bf16 row (16 fragments); the load IS the readiness flag
__device__ __forceinline__ int poll_bf16(const unsigned short* p, bf16x8* d) {
  for (int r = 0; r < kPollCap; ++r) {
    COH_LD16(d[0],  p, 0);   COH_LD16(d[1],  p, 64);  COH_LD16(d[2],  p, 128);
    COH_LD16(d[3],  p, 192); COH_LD16(d[4],  p, 256); COH_LD16(d[5],  p, 320);
    COH_LD16(d[6],  p, 384); COH_LD16(d[7],  p, 448); COH_LD16(d[8],  p, 512);
    COH_LD16(d[9],  p, 576); COH_LD16(d[10], p, 640); COH_LD16(d[11], p, 704);
    COH_LD16(d[12], p, 768); COH_LD16(d[13], p, 832); COH_LD16(d[14], p, 896);
    COH_LD16(d[15], p, 960);
    wait_vm0();
    int stale = 0;
#pragma unroll
    for (int i = 0; i < 16; ++i) {
      u32x4 w = *(const u32x4*)&d[i];
      stale |= (w[0] == kSentB) | (w[1] == kSentB) | (w[2] == kSentB) | (w[3] == kSentB);
    }
    if (!__any(stale)) return 1;
  }
  return 0;
}

// poll one 512-elem fp32 row (16 frags x 2 halves = 32 x 16B loads)
__device__ __forceinline__ int poll_f32(const float* p, f32x4* d) {
  for (int r = 0; r < kPollCap; ++r) {
    COH_LD16(d[0],  p, 0);    COH_LD16(d[1],  p, 16);   COH_LD16(d[2],  p, 128);
    COH_LD16(d[3],  p, 144);  COH_LD16(d[4],  p, 256);  COH_LD16(d[5],  p, 272);
    COH_LD16(d[6],  p, 384);  COH_LD16(d[7],  p, 400);  COH_LD16(d[8],  p, 512);
    COH_LD16(d[9],  p, 528);  COH_LD16(d[10], p, 640);  COH_LD16(d[11], p, 656);
    COH_LD16(d[12], p, 768);  COH_LD16(d[13], p, 784);  COH_LD16(d[14], p, 896);
    COH_LD16(d[15], p, 912);  COH_LD16(d[16], p, 1024); COH_LD16(d[17], p, 1040);
    COH_LD16(d[18], p, 1152); COH_LD16(d[19], p, 1168); COH_LD16(d[20], p, 1280);
    COH_LD16(d[21], p, 1296); COH_LD16(d[22], p, 1408); COH_LD16(d[23], p, 1424);
    COH_LD16(d[24], p, 1536); COH_LD16(d[25], p, 1552); COH_LD16(d[26], p, 1664);
    COH_LD16(d[27], p, 1680); COH_LD16(d[28], p, 1792); COH_LD16(d[29], p, 1808);
    COH_LD16(d[30], p, 1920); COH_LD16(d[31], p, 1936);
    wait_vm0();
    int stale = 0;
#pragma unroll
    for (int i = 0; i < 32; ++i) {
      u32x4 w = *(const u32x4*)&d[i];
      stale |= (w[0] == kSentF) | (w[1] == kSentF) | (w[2] == kSentF) | (w[3] == kSentF);
    }
    if (!__any(stale)) return 1;
  }
  return 0;
}

// pack 8 f32 -> bf16x8 via v_cvt_pk_bf16_f32 (RNE)
__device__ __forceinline__ bf16x8 pk_bf16(f32x4 lo, f32x4 hi) {
  union { u32x4 u; bf16x8 h; } r;
  asm("v_cvt_pk_bf16_f32 %0, %1, %2" : "=v"(r.u[0]) : "v"(lo[0]), "v"(lo[1]));
  asm("v_cvt_pk_bf16_f32 %0, %1, %2" : "=v"(r.u[1]) : "v"(lo[2]), "v"(lo[3]));
  asm("v_cvt_pk_bf16_f32 %0, %1, %2" : "=v"(r.u[2]) : "v"(hi[0]), "v"(hi[1]));
  asm("v_cvt_pk_bf16_f32 %0, %1, %2" : "=v"(r.u[3]) : "v"(hi[2]), "v"(hi[3]));
  return r.h;
}

// ---------------- fill: plain stores (kernel-end flush makes them visible) ----------------
__global__ void fill32(unsigned int* __restrict__ p, unsigned int v, int n) {
  int i = blockIdx.x * blockDim.x + threadIdx.x;
  if (i < n) p[i] = v;
}

// ---------------- fp32 -> bf16 converts ----------------
__global__ void cvt_f32_bf16(const float* __restrict__ in,
                             unsigned short* __restrict__ out, int n4) {
  int i = blockIdx.x * blockDim.x + threadIdx.x;
  if (i >= n4) return;
  float4 v = ((const float4*)in)[i];
  ushort4 o;
  o.x = f2bf(v.x); o.y = f2bf(v.y); o.z = f2bf(v.z); o.w = f2bf(v.w);
  ((ushort4*)out)[i] = o;
}

// x [B][S][I] fp32 -> xbf [S][B][I] bf16 (time-major)
__global__ void cvt_x_t(const float* __restrict__ in,
                        unsigned short* __restrict__ out, int n4) {
  int i4 = blockIdx.x * blockDim.x + threadIdx.x;
  if (i4 >= n4) return;
  int d = i4 * 4;
  int i = d & (kH - 1);
  int rem = d / kH;
  int b = rem & (kB - 1);
  int s = rem / kB;
  float4 v = *(const float4*)(in + ((size_t)b * kS + s) * kH + i);
  ushort4 o;
  o.x = f2bf(v.x); o.y = f2bf(v.y); o.z = f2bf(v.z); o.w = f2bf(v.w);
  *(ushort4*)(out + (size_t)d) = o;
}

// ---------------- fused persistent 2-layer GRU, sentinel-sync ----------------
// blocks 0..127 = layer 0, 128..255 = layer 1. No flags/atomics/drains:
// consumers poll their own MFMA A-fragments for NaN sentinels (h is always
// finite, so NaN == "not yet written"). hs0 = per-t bf16 (L0 out / L1 in);
// L1's self-recurrence reads fp32 h directly from `out` (per-t unique).
__launch_bounds__(256, 1)
__global__ void gru_fused(const unsigned short* __restrict__ xbf,   // [S][B][H]
                          const unsigned short* __restrict__ wih0,  // [3H][H]
                          const unsigned short* __restrict__ whh0,
                          const unsigned short* __restrict__ wih1,
                          const unsigned short* __restrict__ whh1,
                          const float* __restrict__ bih0, const float* __restrict__ bhh0,
                          const float* __restrict__ bih1, const float* __restrict__ bhh1,
                          unsigned short* __restrict__ hs0,    // [S][B][H] bf16
                          float* __restrict__ out) {           // [B][S][H] + [2][B][H]
  const int tid  = threadIdx.x;
  const int lane = tid & 63;
  const int wv   = tid >> 6;            // wave 0..3
  const int layer = blockIdx.x >> 7;
  const int wg    = blockIdx.x & (kNWGL - 1);
  const int j0    = wg * kUPW;

  const unsigned short* wih = layer ? wih1 : wih0;
  const unsigned short* whh = layer ? whh1 : whh0;
  const float* bih = layer ? bih1 : bih0;
  const float* bhh = layer ? bhh1 : bhh0;

  // ---- B-fragments (weights) in registers, loaded once ----
  bf16x8 bx[16], bh[16];
  {
    const int n = lane & 15, hi = lane >> 4;
    if (n < 12) {
      const int orig = (n >> 2) * kH + j0 + (n & 3);  // gate*512 + unit
      const unsigned short* pX = wih + (size_t)orig * kH + hi * 8;
      const unsigned short* pH = whh + (size_t)orig * kH + hi * 8;
#pragma unroll
      for (int kk = 0; kk < 16; ++kk) {
        bx[kk] = *(const bf16x8*)(pX + kk * 32);
        bh[kk] = *(const bf16x8*)(pH + kk * 32);
      }
    } else {
      bf16x8 z = {0, 0, 0, 0, 0, 0, 0, 0};
#pragma unroll
      for (int kk = 0; kk < 16; ++kk) { bx[kk] = z; bh[kk] = z; }
    }
  }

  // gate-phase assignment: thread -> (batch gb, unit gu)
  const int gb = tid & 63;
  const int gu = wv;
  const float bihr = bih[j0 + gu], bihz = bih[kH + j0 + gu], bihn = bih[2 * kH + j0 + gu];
  const float bhhr = bhh[j0 + gu], bhhz = bhh[kH + j0 + gu], bhhn = bhh[2 * kH + j0 + gu];
  float hprev = 0.0f;

  __shared__ float gxl[64][17];   // padded exchange
  __shared__ float ghl[64][17];
  __shared__ unsigned short hl[64][4];
  __shared__ float hlf[64][4];

  const int b0   = wv * 16;             // M-tile batch base for this wave
  const int arow = b0 + (lane & 15);    // A row = batch
  const int ahi  = (lane >> 4) * 8;     // k sub-offset
  const int n_   = lane & 15;
  const int mb   = b0 + (lane >> 4) * 4;

  for (int t = 0; t < kS; ++t) {
    // ---- layer 0: input GEMM first (x L2-cached, dependency-free) ----
    f32x4 accx = {0.f, 0.f, 0.f, 0.f};
    if (layer == 0) {
      const unsigned short* pAX = xbf + ((size_t)t * kB + arow) * kH + ahi;
#pragma unroll
      for (int kk = 0; kk < 16; ++kk) {
        bf16x8 ax = *(const bf16x8*)(pAX + kk * 32);
        accx = __builtin_amdgcn_mfma_f32_16x16x32_bf16(ax, bx[kk], accx, 0, 0, 0);
      }
    }

    // ---- sentinel-polled operand loads + recurrent GEMMs ----
    int ok = 1;
    f32x4 acch = {0.f, 0.f, 0.f, 0.f};
    if (layer == 0) {
      if (t > 0) {
        bf16x8 ah[16];
        ok = poll_bf16(hs0 + ((size_t)(t - 1) * kB + arow) * kH + ahi, ah);
#pragma unroll
        for (int kk = 0; kk < 16; ++kk)
          acch = __builtin_amdgcn_mfma_f32_16x16x32_bf16(ah[kk], bh[kk], acch, 0, 0, 0);
      }
    } else {
      bf16x8 axv[16];
      ok = poll_bf16(hs0 + ((size_t)t * kB + arow) * kH + ahi, axv);
#pragma unroll
      for (int kk = 0; kk < 16; ++kk)
        accx = __builtin_amdgcn_mfma_f32_16x16x32_bf16(axv[kk], bx[kk], accx, 0, 0, 0);
      if (t > 0) {
        f32x4 fr[32];
        ok &= poll_f32(out + ((size_t)arow * kS + (t - 1)) * kH + ahi, fr);
#pragma unroll
        for (int kk = 0; kk < 16; ++kk) {
          bf16x8 ah = pk_bf16(fr[2 * kk], fr[2 * kk + 1]);
          acch = __builtin_amdgcn_mfma_f32_16x16x32_bf16(ah, bh[kk], acch, 0, 0, 0);
        }
      }
    }

    // ---- exchange via LDS: C[m][n] -> [batch][gate-row] ----
#pragma unroll
    for (int r = 0; r < 4; ++r) {
      gxl[mb + r][n_] = accx[r];
      ghl[mb + r][n_] = acch[r];
    }
    if (!__syncthreads_and(ok)) return;  // doubles as exchange barrier + bail

    // ---- gate math (fp32) ----
    {
      const float xr = gxl[gb][gu]     + bihr;
      const float xz = gxl[gb][4 + gu] + bihz;
      const float xn = gxl[gb][8 + gu] + bihn;
      const float hr = ghl[gb][gu]     + bhhr;
      const float hzv = ghl[gb][4 + gu] + bhhz;
      const float hn = ghl[gb][8 + gu] + bhhn;
      const float r = 1.0f / (1.0f + __expf(-(xr + hr)));
      const float z = 1.0f / (1.0f + __expf(-(xz + hzv)));
      const float nn = tanhf(xn + r * hn);
      const float hnew = (1.0f - z) * nn + z * hprev;
      hprev = hnew;
      hl[gb][gu] = f2bf(hnew);
      hlf[gb][gu] = hnew;
      if (t == kS - 1)  // h_n epilogue (plain store; flushed at kernel end)
        out[(size_t)kB * kS * kH + (size_t)layer * kB * kH + (size_t)gb * kH + j0 + gu] = hnew;
    }
    __syncthreads();

    // ---- publish (wave 0): write-through stores, NO drain, NO flags ----
    if (tid < 64) {
      if (layer == 0) {
        unsigned long long pk = *(const unsigned long long*)&hl[tid][0];
        st_u64_coh(hs0 + ((size_t)t * kB + tid) * kH + j0, pk);
      } else {
        f32x4 o4 = *(const f32x4*)&hlf[tid][0];
        st_f32x4_coh(out + ((size_t)tid * kS + t) * kH + j0, o4);  // [b][t][h]
      }
    }
    // no trailing barrier needed: hl/hlf next written only after the next
    // __syncthreads_and, which wave 0 joins after issuing its stores.
  }
}

extern "C" void kernel_launch(void* const* d_in, const int* in_sizes, int n_in,
                              void* d_out, int out_size, void* d_ws, size_t ws_size,
                              hipStream_t stream) {
  const float* x     = (const float*)d_in[0];
  const float* w_ih0 = (const float*)d_in[1];
  const float* w_hh0 = (const float*)d_in[2];
  const float* b_ih0 = (const float*)d_in[3];
  const float* b_hh0 = (const float*)d_in[4];
  const float* w_ih1 = (const float*)d_in[5];
  const float* w_hh1 = (const float*)d_in[6];
  const float* b_ih1 = (const float*)d_in[7];
  const float* b_hh1 = (const float*)d_in[8];
  float* out = (float*)d_out;

  // ---- workspace layout (ushort elems unless noted) ----
  unsigned short* ws = (unsigned short*)d_ws;
  const size_t nX = (size_t)kB * kS * kH;   // 33,554,432
  const size_t nW = (size_t)3 * kH * kH;    // 786,432
  unsigned short* xbf   = ws;
  unsigned short* wih0b = xbf + nX;
  unsigned short* whh0b = wih0b + nW;
  unsigned short* wih1b = whh0b + nW;
  unsigned short* whh1b = wih1b + nW;
  unsigned short* hs0   = whh1b + nW;       // nX elems

  // sentinel pre-fills (REQUIRED each launch: ws/out hold stale prior-replay
  // data; NaN marks "not yet written this launch")
  {
    int nh = (int)(nX / 2);                      // hs0 as u32
    fill32<<<(nh + 255) / 256, 256, 0, stream>>>((unsigned int*)hs0, kSentB, nh);
    int no = (int)nX;                            // out[B][S][H] as u32
    fill32<<<(no + 255) / 256, 256, 0, stream>>>((unsigned int*)out, kSentF, no);
  }
  // converts
  {
    int n4 = (int)(nX / 4);
    cvt_x_t<<<n4 / 256, 256, 0, stream>>>(x, xbf, n4);
    int w4 = (int)(nW / 4);
    cvt_f32_bf16<<<w4 / 256, 256, 0, stream>>>(w_ih0, wih0b, w4);
    cvt_f32_bf16<<<w4 / 256, 256, 0, stream>>>(w_hh0, whh0b, w4);
    cvt_f32_bf16<<<w4 / 256, 256, 0, stream>>>(w_ih1, wih1b, w4);
    cvt_f32_bf16<<<w4 / 256, 256, 0, stream>>>(w_hh1, whh1b, w4);
  }

  // fused persistent GRU — plain launch (256 blocks on 256 CUs, 1/CU)
  gru_fused<<<dim3(2 * kNWGL), dim3(256), 0, stream>>>(
      xbf, wih0b, whh0b, wih1b, whh1b,
      b_ih0, b_hh0, b_ih1, b_hh1,
      hs0, out);
}

// Round 11
// 5222.438 us; speedup vs baseline: 2.0187x; 1.6074x over previous
//
#include <hip/hip_runtime.h>
#include <hip/hip_bf16.h>
#include <cstddef>

typedef __attribute__((ext_vector_type(8))) short bf16x8;
typedef __attribute__((ext_vector_type(4))) float f32x4;
typedef __attribute__((ext_vector_type(4))) unsigned int u32x4;

constexpr int kB = 64;      // batch
constexpr int kS = 1024;    // seq len
constexpr int kH = 512;     // hidden (== input size)
constexpr int kNBG = 4;     // batch groups (16 batches each)
constexpr int kNUG = 32;    // unit groups per layer (16 units each)
constexpr int kHst = 520;   // padded LDS h-stage row stride (elems)
constexpr unsigned kDone4 = 0x01010101u;
constexpr int kSpinCap = 1 << 16;  // fail-fast

__device__ __forceinline__ unsigned short f2bf(float f) {
  unsigned int u = __float_as_uint(f);
  u += 0x7FFFu + ((u >> 16) & 1u);   // round-to-nearest-even
  return (unsigned short)(u >> 16);
}

// ---------------- coherent (IF$-level) helpers: sc0 sc1 bypass L1+L2 ----------------
__device__ __forceinline__ void st_u32_coh(unsigned int* p, unsigned int v) {
  asm volatile("global_store_dword %0, %1, off sc0 sc1" ::"v"(p), "v"(v) : "memory");
}
__device__ __forceinline__ void st_u64_coh(void* p, unsigned long long v) {
  asm volatile("global_store_dwordx2 %0, %1, off sc0 sc1" ::"v"(p), "v"(v) : "memory");
}
// drain wave's outstanding stores (IF$ ack), then set done-byte
__device__ __forceinline__ void st_flag_release8(unsigned char* p, unsigned int v) {
  asm volatile("s_waitcnt vmcnt(0)\n\tglobal_store_byte %0, %1, off sc0 sc1"
               ::"v"(p), "v"(v) : "memory");
}

#define COH_LD16(dst, p, OFF)                                             \
  asm volatile("global_load_dwordx4 %0, %1, off offset:" #OFF " sc0 sc1"  \
               : "=v"(dst) : "v"(p) : "memory")

__device__ __forceinline__ void wait_vm0(void) {
  asm volatile("s_waitcnt vmcnt(0)" ::: "memory");
  __builtin_amdgcn_sched_barrier(0);  // rule #18
}

// single-thread poll of 32 contiguous done-bytes (2 x dwordx4), capped
__device__ __forceinline__ int poll32(const unsigned char* p) {
  for (int i = 0; i < kSpinCap; ++i) {
    u32x4 a, b;
    asm volatile(
        "global_load_dwordx4 %0, %2, off sc0 sc1\n\t"
        "global_load_dwordx4 %1, %2, off offset:16 sc0 sc1\n\t"
        "s_waitcnt vmcnt(0)"
        : "=v"(a), "=v"(b) : "v"(p) : "memory");
    if (a[0] == kDone4 && a[1] == kDone4 && a[2] == kDone4 && a[3] == kDone4 &&
        b[0] == kDone4 && b[1] == kDone4 && b[2] == kDone4 && b[3] == kDone4)
      return 1;
  }
  return 0;
}

// ---------------- init: coherent zeros (flags) ----------------
__global__ void init_coh(unsigned int* __restrict__ zbase, int n) {
  int i = blockIdx.x * blockDim.x + threadIdx.x;
  if (i < n) st_u32_coh(zbase + i, 0u);
}

// ---------------- fp32 -> bf16 converts ----------------
__global__ void cvt_f32_bf16(const float* __restrict__ in,
                             unsigned short* __restrict__ out, int n4) {
  int i = blockIdx.x * blockDim.x + threadIdx.x;
  if (i >= n4) return;
  float4 v = ((const float4*)in)[i];
  ushort4 o;
  o.x = f2bf(v.x); o.y = f2bf(v.y); o.z = f2bf(v.z); o.w = f2bf(v.w);
  ((ushort4*)out)[i] = o;
}

// x [B][S][I] fp32 -> xbf [S][B][I] bf16 (time-major)
__global__ void cvt_x_t(const float* __restrict__ in,
                        unsigned short* __restrict__ out, int n4) {
  int i4 = blockIdx.x * blockDim.x + threadIdx.x;
  if (i4 >= n4) return;
  int d = i4 * 4;
  int i = d & (kH - 1);
  int rem = d / kH;
  int b = rem & (kB - 1);
  int s = rem / kB;
  float4 v = *(const float4*)(in + ((size_t)b * kS + s) * kH + i);
  ushort4 o;
  o.x = f2bf(v.x); o.y = f2bf(v.y); o.z = f2bf(v.z); o.w = f2bf(v.w);
  *(ushort4*)(out + (size_t)d) = o;
}

// ---------------- fused persistent 2-layer GRU, batch-group partition ----------------
// 256 WGs: layer = wgid>>7; bg = wgid&3 (16 batches); ug = (wgid&127)>>2
// (16 units). Recurrence is elementwise in batch -> each WG only ever needs
// h[its 16 batches][all 512], staged ONCE into LDS and shared by 4 waves
// (4x less IF$ traffic than units-only split). Waves split over N: wave wv
// owns units ug*16+wv*4..+3 (12 gate rows as VGPR B-frags, R7 shape).
// Sync: 32 done-bytes per (layer,bg,t), single-poller, fail-fast capped.
__launch_bounds__(256, 1)
__global__ void gru_fused(const unsigned short* __restrict__ xbf,   // [S][B][H]
                          const unsigned short* __restrict__ wih0,  // [3H][H]
                          const unsigned short* __restrict__ whh0,
                          const unsigned short* __restrict__ wih1,
                          const unsigned short* __restrict__ whh1,
                          const float* __restrict__ bih0, const float* __restrict__ bhh0,
                          const float* __restrict__ bih1, const float* __restrict__ bhh1,
                          unsigned short* __restrict__ hs0,    // [S][B][H] bf16
                          unsigned short* __restrict__ h1buf,  // [2][B][H] bf16
                          unsigned char* __restrict__ f0,      // [S][4][32] done-bytes
                          unsigned char* __restrict__ f1,
                          float* __restrict__ out) {
  const int tid  = threadIdx.x;
  const int lane = tid & 63;
  const int wv   = tid >> 6;                  // wave 0..3
  const int wgid = blockIdx.x;
  const int layer = wgid >> 7;
  const int bg    = wgid & 3;                 // batch group
  const int ug    = (wgid & 127) >> 2;        // unit group
  const int bgb0  = bg * 16;
  const int j0w   = ug * 16 + wv * 4;         // this wave's 4 units

  const unsigned short* wih = layer ? wih1 : wih0;
  const unsigned short* whh = layer ? whh1 : whh0;
  const float* bih = layer ? bih1 : bih0;
  const float* bhh = layer ? bhh1 : bhh0;

  // ---- B-fragments (12 gate rows of this wave's 4 units) in VGPRs ----
  bf16x8 bx[16], bh[16];
  {
    const int n = lane & 15, hi = lane >> 4;
    if (n < 12) {
      const int orig = (n >> 2) * kH + j0w + (n & 3);  // gate*512 + unit
      const unsigned short* pX = wih + (size_t)orig * kH + hi * 8;
      const unsigned short* pH = whh + (size_t)orig * kH + hi * 8;
#pragma unroll
      for (int kk = 0; kk < 16; ++kk) {
        bx[kk] = *(const bf16x8*)(pX + kk * 32);
        bh[kk] = *(const bf16x8*)(pH + kk * 32);
      }
    } else {
      bf16x8 z = {0, 0, 0, 0, 0, 0, 0, 0};
#pragma unroll
      for (int kk = 0; kk < 16; ++kk) { bx[kk] = z; bh[kk] = z; }
    }
  }

  // gate thread mapping: thread -> (batch gb in group, unit guu 0..15)
  const int gb  = tid & 15;
  const int guu = tid >> 4;
  const int unit = ug * 16 + guu;
  const float bihr = bih[unit], bihz = bih[kH + unit], bihn = bih[2 * kH + unit];
  const float bhhr = bhh[unit], bhhz = bhh[kH + unit], bhhn = bhh[2 * kH + unit];
  float hprev = 0.0f;

  __shared__ unsigned short hA[16][kHst];  // staged h_{t-1}[16 batches][512]
  __shared__ unsigned short hX[16][kHst];  // staged hs0[t] (layer 1 only)
  __shared__ float gxl[16][52];            // exchange: 4 waves x 12 cols
  __shared__ float ghl[16][52];
  __shared__ unsigned short hl[16][20];    // padded gather for publish
  __shared__ float hlf[16][20];

  // A-fragment lane coords (M = 16 batches of this group)
  const int n_  = lane & 15;
  const int ahi = (lane >> 4) * 8;
  // stage lane coords: lane -> (row, 32-col segment)
  const int srow  = lane & 15;
  const int scol0 = wv * 128 + (lane >> 4) * 32;

  unsigned char* myf = (layer ? f1 : f0);

  for (int t = 0; t < kS; ++t) {
    // ---- layer 0: input GEMM pre-poll (x L2/L1-cached, dependency-free) ----
    f32x4 accx = {0.f, 0.f, 0.f, 0.f};
    if (layer == 0) {
      const unsigned short* pAX = xbf + ((size_t)t * kB + bgb0 + n_) * kH + ahi;
#pragma unroll
      for (int kk = 0; kk < 16; ++kk) {
        bf16x8 ax = *(const bf16x8*)(pAX + kk * 32);
        accx = __builtin_amdgcn_mfma_f32_16x16x32_bf16(ax, bx[kk], accx, 0, 0, 0);
      }
    }

    // ---- wait: single poller per dependency (32 bytes each) ----
    int ok = 1;
    if (layer == 0) {
      if (t > 0 && tid == 0) ok = poll32(f0 + ((size_t)(t - 1) * kNBG + bg) * kNUG);
    } else {
      if (tid == 0) ok = poll32(f0 + ((size_t)t * kNBG + bg) * kNUG);
      else if (t > 0 && tid == 64) ok = poll32(f1 + ((size_t)(t - 1) * kNBG + bg) * kNUG);
    }
    if (!__syncthreads_and(ok)) return;  // fail-fast bail

    // ---- stage h into LDS (16 KB once per WG, shared by 4 waves) ----
    bf16x8 tA[4], tX[4];
    if (t > 0) {
      const unsigned short* sp =
          ((layer == 0) ? hs0 + ((size_t)(t - 1) * kB + bgb0 + srow) * kH
                        : h1buf + ((size_t)((t - 1) & 1) * kB + bgb0 + srow) * kH) + scol0;
      COH_LD16(tA[0], sp, 0); COH_LD16(tA[1], sp, 16);
      COH_LD16(tA[2], sp, 32); COH_LD16(tA[3], sp, 48);
    }
    if (layer == 1) {
      const unsigned short* sx =
          hs0 + ((size_t)t * kB + bgb0 + srow) * kH + scol0;
      COH_LD16(tX[0], sx, 0); COH_LD16(tX[1], sx, 16);
      COH_LD16(tX[2], sx, 32); COH_LD16(tX[3], sx, 48);
    }
    wait_vm0();
    if (t > 0) {
#pragma unroll
      for (int it = 0; it < 4; ++it)
        *(bf16x8*)&hA[srow][scol0 + it * 8] = tA[it];
    }
    if (layer == 1) {
#pragma unroll
      for (int it = 0; it < 4; ++it)
        *(bf16x8*)&hX[srow][scol0 + it * 8] = tX[it];
    }
    __syncthreads();

    // ---- GEMMs from LDS stage ----
    if (layer == 1) {
#pragma unroll
      for (int kk = 0; kk < 16; ++kk) {
        bf16x8 axv = *(const bf16x8*)&hX[n_][kk * 32 + ahi];
        accx = __builtin_amdgcn_mfma_f32_16x16x32_bf16(axv, bx[kk], accx, 0, 0, 0);
      }
    }
    f32x4 acch = {0.f, 0.f, 0.f, 0.f};
    if (t > 0) {
#pragma unroll
      for (int kk = 0; kk < 16; ++kk) {
        bf16x8 ahv = *(const bf16x8*)&hA[n_][kk * 32 + ahi];
        acch = __builtin_amdgcn_mfma_f32_16x16x32_bf16(ahv, bh[kk], acch, 0, 0, 0);
      }
    }
    // exchange write: C row m=(lane>>4)*4+r (batch), col wv*12 + n (gate-row)
    if (n_ < 12) {
      const int m0 = (lane >> 4) * 4;
#pragma unroll
      for (int r = 0; r < 4; ++r) {
        gxl[m0 + r][wv * 12 + n_] = accx[r];
        ghl[m0 + r][wv * 12 + n_] = acch[r];
      }
    }
    __syncthreads();

    // ---- gates: thread (gb, guu); source wave uw = guu>>2, du = guu&3 ----
    {
      const int c0 = (guu >> 2) * 12, du = guu & 3;
      const float xr = gxl[gb][c0 + du]     + bihr;
      const float xz = gxl[gb][c0 + 4 + du] + bihz;
      const float xn = gxl[gb][c0 + 8 + du] + bihn;
      const float hr = ghl[gb][c0 + du]     + bhhr;
      const float hzv = ghl[gb][c0 + 4 + du] + bhhz;
      const float hn = ghl[gb][c0 + 8 + du] + bhhn;
      const float r = 1.0f / (1.0f + __expf(-(xr + hr)));
      const float z = 1.0f / (1.0f + __expf(-(xz + hzv)));
      const float nn = tanhf(xn + r * hn);
      const float hnew = (1.0f - z) * nn + z * hprev;
      hprev = hnew;
      hl[gb][guu] = f2bf(hnew);
      if (layer == 1) hlf[gb][guu] = hnew;
      if (t == kS - 1)  // h_n epilogue (plain store, flushed at kernel end)
        out[(size_t)kB * kS * kH + (size_t)layer * kB * kH +
            (size_t)(bgb0 + gb) * kH + unit] = hnew;
    }
    __syncthreads();

    // ---- publish: wave 0 -> h (coherent); wave 1 -> out fp32 (plain) ----
    if (tid < 64) {
      const int b = tid >> 2, q = tid & 3;
      unsigned long long pk = *(const unsigned long long*)&hl[b][q * 4];
      if (layer == 0)
        st_u64_coh(hs0 + ((size_t)t * kB + bgb0 + b) * kH + ug * 16 + q * 4, pk);
      else
        st_u64_coh(h1buf + ((size_t)(t & 1) * kB + bgb0 + b) * kH + ug * 16 + q * 4, pk);
    } else if (tid < 128 && layer == 1) {
      const int b = (tid - 64) >> 2, q = (tid - 64) & 3;
      *(float4*)(out + ((size_t)(bgb0 + b) * kS + t) * kH + ug * 16 + q * 4) =
          *(const float4*)&hlf[b][q * 4];  // [b][t][h]
    }
    if (tid == 0)
      st_flag_release8(myf + ((size_t)t * kNBG + bg) * kNUG + ug, 1u);
    // no trailing barrier: next-iteration LDS writes are behind the next
    // poll/stage barriers, which wave 0 joins only after publish+flag.
  }
}

extern "C" void kernel_launch(void* const* d_in, const int* in_sizes, int n_in,
                              void* d_out, int out_size, void* d_ws, size_t ws_size,
                              hipStream_t stream) {
  const float* x     = (const float*)d_in[0];
  const float* w_ih0 = (const float*)d_in[1];
  const float* w_hh0 = (const float*)d_in[2];
  const float* b_ih0 = (const float*)d_in[3];
  const float* b_hh0 = (const float*)d_in[4];
  const float* w_ih1 = (const float*)d_in[5];
  const float* w_hh1 = (const float*)d_in[6];
  const float* b_ih1 = (const float*)d_in[7];
  const float* b_hh1 = (const float*)d_in[8];
  float* out = (float*)d_out;

  // ---- workspace layout (ushort elems unless noted) ----
  unsigned short* ws = (unsigned short*)d_ws;
  const size_t nX = (size_t)kB * kS * kH;   // 33,554,432
  const size_t nW = (size_t)3 * kH * kH;    // 786,432
  unsigned short* xbf   = ws;
  unsigned short* wih0b = xbf + nX;
  unsigned short* whh0b = wih0b + nW;
  unsigned short* wih1b = whh0b + nW;
  unsigned short* whh1b = wih1b + nW;
  unsigned short* hs0   = whh1b + nW;             // nX elems
  unsigned short* h1buf = hs0 + nX;               // 2*B*H
  unsigned char*  f0    = (unsigned char*)(h1buf + 2 * kB * kH);  // S*4*32
  unsigned char*  f1    = f0 + (size_t)kS * kNBG * kNUG;

  // zero both flag arrays (contiguous 256KB) coherently each launch
  {
    int nz = (int)(2 * (size_t)kS * kNBG * kNUG / 4);   // 65536 u32
    init_coh<<<(nz + 255) / 256, 256, 0, stream>>>((unsigned int*)f0, nz);
  }
  // converts
  {
    int n4 = (int)(nX / 4);
    cvt_x_t<<<n4 / 256, 256, 0, stream>>>(x, xbf, n4);
    int w4 = (int)(nW / 4);
    cvt_f32_bf16<<<w4 / 256, 256, 0, stream>>>(w_ih0, wih0b, w4);
    cvt_f32_bf16<<<w4 / 256, 256, 0, stream>>>(w_hh0, whh0b, w4);
    cvt_f32_bf16<<<w4 / 256, 256, 0, stream>>>(w_ih1, wih1b, w4);
    cvt_f32_bf16<<<w4 / 256, 256, 0, stream>>>(w_hh1, whh1b, w4);
  }

  // fused persistent GRU — 256 blocks (capacity >= grid, all co-resident)
  gru_fused<<<dim3(256), dim3(256), 0, stream>>>(
      xbf, wih0b, whh0b, wih1b, whh1b,
      b_ih0, b_hh0, b_ih1, b_hh1,
      hs0, h1buf, f0, f1, out);
}